// Round 8
// baseline (1286.906 us; speedup 1.0000x reference)
//
#include <hip/hip_runtime.h>

#define NROWS 32768
#define KC 8192
#define DDIM 256
#define D4 64
#define CAP 64
#define DELTA 1e-3f
#define MT 128
#define NSEG 8
#define SEGC (KC / NSEG)   // 1024 codes per block
#define PAN 64             // codes per panel
#define NPAN (SEGC / PAN)  // 16 panels

typedef _Float16 half8 __attribute__((ext_vector_type(8)));
typedef float f32x4 __attribute__((ext_vector_type(4)));
typedef unsigned int uint;
typedef const __attribute__((address_space(1))) unsigned int* gptr_u32;
typedef __attribute__((address_space(3))) unsigned int* lptr_u32;

union H4 { ushort4 u; _Float16 h[4]; };

// fmax-reduce over each 16-lane group via DPP row_ror (pure VALU)
template <int CTRL>
__device__ __forceinline__ float rormax_step(float x) {
  const int v = __builtin_amdgcn_mov_dpp(__float_as_int(x), CTRL, 0xf, 0xf, true);
  return fmaxf(x, __int_as_float(v));
}
__device__ __forceinline__ float redmax16(float x) {
  x = rormax_step<0x121>(x);  // row_ror:1
  x = rormax_step<0x122>(x);  // row_ror:2
  x = rormax_step<0x124>(x);  // row_ror:4
  x = rormax_step<0x128>(x);  // row_ror:8
  return x;
}

// ---------------- kernel 1: bit-exact numpy pairwise row norm ----------------
__global__ __launch_bounds__(256) void vq_znorm(const float* __restrict__ z,
                                                float* __restrict__ An) {
#pragma clang fp contract(off)
  const int row = blockIdx.x * 256 + threadIdx.x;
  const float4* p4 = (const float4*)(z + (size_t)row * 256);
  float halves[2];
#pragma unroll
  for (int h = 0; h < 2; ++h) {
    float r[8];
    float4 a = p4[h * 32 + 0], b = p4[h * 32 + 1];
    r[0] = a.x * a.x; r[1] = a.y * a.y; r[2] = a.z * a.z; r[3] = a.w * a.w;
    r[4] = b.x * b.x; r[5] = b.y * b.y; r[6] = b.z * b.z; r[7] = b.w * b.w;
    for (int i = 1; i < 16; ++i) {  // 8-elem chunks in numpy pairwise order
      a = p4[h * 32 + i * 2];
      b = p4[h * 32 + i * 2 + 1];
      r[0] += a.x * a.x; r[1] += a.y * a.y; r[2] += a.z * a.z; r[3] += a.w * a.w;
      r[4] += b.x * b.x; r[5] += b.y * b.y; r[6] += b.z * b.z; r[7] += b.w * b.w;
    }
    halves[h] = ((r[0] + r[1]) + (r[2] + r[3])) + ((r[4] + r[5]) + (r[6] + r[7]));
  }
  An[row] = halves[0] + halves[1];
}

// ---------------- kernel 2: f32 -> f16 conversion (+ scale e by 2^13) + init ----------------
__global__ __launch_bounds__(256) void vq_convert(const float* __restrict__ z,
                                                  const float* __restrict__ emb,
                                                  _Float16* __restrict__ z16,
                                                  _Float16* __restrict__ e16,
                                                  int* __restrict__ cnt,
                                                  uint* __restrict__ rowmin) {
  const int tid = blockIdx.x * 256 + threadIdx.x;  // 524288 threads
  const float4* z4 = (const float4*)z;
  const float4* e4 = (const float4*)emb;
  ushort4* z16u = (ushort4*)z16;
  ushort4* e16u = (ushort4*)e16;
#pragma unroll
  for (int t = 0; t < 4; ++t) {
    const int i = tid + t * 524288;
    const float4 v = z4[i];
    H4 o;
    o.h[0] = (_Float16)v.x; o.h[1] = (_Float16)v.y;
    o.h[2] = (_Float16)v.z; o.h[3] = (_Float16)v.w;
    z16u[i] = o.u;
  }
  {
    const int i = tid;  // 524288 = 8192*64
    const float4 v = e4[i];
    H4 o;
    o.h[0] = (_Float16)(v.x * 8192.0f); o.h[1] = (_Float16)(v.y * 8192.0f);
    o.h[2] = (_Float16)(v.z * 8192.0f); o.h[3] = (_Float16)(v.w * 8192.0f);
    e16u[i] = o.u;
  }
  if (tid < NROWS) { cnt[tid] = 0; rowmin[tid] = 0x7F800000u; }  // +inf
}

// ---------------- kernel 3: two-pass z-stationary f16 MFMA GEMM + filter ----------------
// grid 2048 = 256 M-tiles(128 rows) x 8 N-segments; seg = bid&7 (XCD-affine -> segment L2-hot).
// 4 waves = 2 row-halves x 2 code-halves; wave: 64 rows (af[4][8] regs, full K) x 32 codes.
// vp 0..15  (pass A): MFMA + 32 fmax/panel. At vp=15: redmax16 once, atomicMin (no readback).
// vp 16..31 (pass B): re-stage panels (L2-hot), MFMA + threshold compare + rare append.
__global__ __launch_bounds__(256, 2) void vq_gemm_filter(
    const _Float16* __restrict__ z16, const _Float16* __restrict__ e16,
    const float* __restrict__ An, uint* __restrict__ rowmin,
    int* __restrict__ cnt, uint* __restrict__ list) {
  __shared__ _Float16 smem[32768];  // 64KB: z-stage, then e-panel dbuf (2x32KB)
  const int bid = blockIdx.x;
  const int seg = bid & 7, mIdx = bid >> 3;
  const int brow = mIdx * MT;
  const int c0seg = seg * SEGC;
  const int tid = threadIdx.x;
  const int lane = tid & 63, w = tid >> 6;
  const int l15 = lane & 15, l4 = lane >> 4;
  const int wr = w >> 1, wc = w & 1;
  const int wrow = wr * 64;

  // ---- stage z tile (128x256 f16 = 64KB), source pre-swizzled: slotL = slotP ^ (row&31)
#pragma unroll
  for (int i = 0; i < 16; ++i) {
    const int c = tid + 256 * i;  // [0,4096) 16B chunks
    const int r = c >> 5, sl = (c & 31) ^ (r & 31);
    __builtin_amdgcn_global_load_lds(
        (gptr_u32)(z16 + (size_t)(brow + r) * DDIM + sl * 8),
        (lptr_u32)(smem + c * 8), 16, 0, 0);
  }
  __syncthreads();
  // ---- af register-resident: rows wrow + m*16 + l15, full K
  half8 af[4][8];
#pragma unroll
  for (int m = 0; m < 4; ++m) {
    const int row = wrow + m * 16 + l15;
#pragma unroll
    for (int k = 0; k < 8; ++k) {
      const int sl = (k * 4 + l4) ^ (row & 31);
      af[m][k] = *(const half8*)(smem + row * 256 + sl * 8);
    }
  }
  __syncthreads();  // all reads of z region done before panel staging overwrites

  float An_r[4][4];
#pragma unroll
  for (int m = 0; m < 4; ++m) {
    const f32x4 a4 = *(const f32x4*)(An + brow + wrow + m * 16 + l4 * 4);
#pragma unroll
    for (int r = 0; r < 4; ++r) An_r[m][r] = a4[r];
  }

  float tm[4][4];   // pass A: running max of acc (score min)
  float ls[4][4];   // local best score per (m,r)
  float g[4][4];    // stale global rowmin
  float Lthr[4][4]; // pass B acc-domain append limit
#pragma unroll
  for (int m = 0; m < 4; ++m)
#pragma unroll
    for (int r = 0; r < 4; ++r) tm[m][r] = -3.4e38f;

  // prologue: stage panel 0 into buffer 0
#pragma unroll
  for (int i = 0; i < 8; ++i) {
    const int c = tid + 256 * i;  // [0,2048)
    const int r = c >> 5, sl = (c & 31) ^ (r & 31);
    __builtin_amdgcn_global_load_lds(
        (gptr_u32)(e16 + (size_t)(c0seg + r) * DDIM + sl * 8),
        (lptr_u32)(smem + c * 8), 16, 0, 0);
  }
  __syncthreads();

  for (int vp = 0; vp < 2 * NPAN; ++vp) {
    const int p = vp & 15;
    const int curoff = (vp & 1) << 14;  // 16384 f16 per buffer
    if (vp + 1 < 2 * NPAN) {  // stage next panel ((vp+1)&15) into other buffer
      const int cb = c0seg + ((vp + 1) & 15) * PAN;
      const int nxtoff = curoff ^ 16384;
#pragma unroll
      for (int i = 0; i < 8; ++i) {
        const int c = tid + 256 * i;
        const int r = c >> 5, sl = (c & 31) ^ (r & 31);
        __builtin_amdgcn_global_load_lds(
            (gptr_u32)(e16 + (size_t)(cb + r) * DDIM + sl * 8),
            (lptr_u32)(smem + nxtoff + c * 8), 16, 0, 0);
      }
    }
    f32x4 acc[4][2] = {{{0.f}}};
#pragma unroll
    for (int k = 0; k < 8; ++k) {
      half8 bf[2];
#pragma unroll
      for (int n = 0; n < 2; ++n) {
        const int crow = wc * 32 + n * 16 + l15;
        const int sl = (k * 4 + l4) ^ (crow & 31);
        bf[n] = *(const half8*)(smem + curoff + crow * 256 + sl * 8);
      }
#pragma unroll
      for (int m = 0; m < 4; ++m)
#pragma unroll
        for (int n = 0; n < 2; ++n)
          acc[m][n] = __builtin_amdgcn_mfma_f32_16x16x32_f16(af[m][k], bf[n], acc[m][n], 0, 0, 0);
    }

    if (vp < NPAN) {
      // ---- pass A epilogue: 32 scalar fmax, nothing else ----
#pragma unroll
      for (int m = 0; m < 4; ++m)
#pragma unroll
        for (int r = 0; r < 4; ++r)
          tm[m][r] = fmaxf(tm[m][r], fmaxf(acc[m][0][r], acc[m][1][r]));
      if (vp == NPAN - 1) {
        // finalize local min, publish (fire-and-forget), fetch stale global
#pragma unroll
        for (int m = 0; m < 4; ++m)
#pragma unroll
          for (int r = 0; r < 4; ++r) {
            const float pmax = redmax16(tm[m][r]);
            ls[m][r] = fmaf(pmax, -0x1p-12f, An_r[m][r]);
            const int row = brow + wrow + m * 16 + l4 * 4 + r;
            if (l15 == 0)  // scores > 0 -> uint order == float order; no readback
              atomicMin(rowmin + row, __float_as_uint(ls[m][r]));
            g[m][r] = __uint_as_float(rowmin[row]);
          }
      }
    } else {
      if (vp == NPAN) {
#pragma unroll
        for (int m = 0; m < 4; ++m)
#pragma unroll
          for (int r = 0; r < 4; ++r)
            Lthr[m][r] = (An_r[m][r] - fminf(g[m][r], ls[m][r]) - DELTA) * 4096.0f;
      }
      // ---- pass B epilogue: 32 compares + rare appends ----
#pragma unroll
      for (int m = 0; m < 4; ++m)
#pragma unroll
        for (int n = 0; n < 2; ++n)
#pragma unroll
          for (int r = 0; r < 4; ++r) {
            if (acc[m][n][r] >= Lthr[m][r]) {
              const int row = brow + wrow + m * 16 + l4 * 4 + r;
              const int code = c0seg + p * PAN + wc * 32 + n * 16 + l15;
              const int pos = atomicAdd(cnt + row, 1);
              if (pos < CAP) list[(size_t)row * CAP + pos] = (uint)code;
            }
          }
    }
    __syncthreads();  // next-panel staging landed; cur buffer reusable
  }
}

// ---------------- kernel 4: exact recheck (bit-exact np chain) + gather ----------------
__global__ __launch_bounds__(256) void vq_recheck_gather(
    const float* __restrict__ z, const float* __restrict__ emb,
    const float* __restrict__ An, const int* __restrict__ cnt,
    const uint* __restrict__ list, float* __restrict__ out) {
  const int row = blockIdx.x * 4 + (threadIdx.x >> 6);
  const int lane = threadIdx.x & 63;
  const int nc = cnt[row];
  const float Ar = An[row];
  const float4* z4r = (const float4*)z + (size_t)row * D4;
  const float4* e4 = (const float4*)emb;
  float bs = 3.4e38f;
  int bi = 0x7fffffff;
  if (nc <= CAP) {
    // one candidate per lane (nc small); exact-eval all of them
    if (lane < nc) {
      const int code = (int)list[(size_t)row * CAP + lane];
      float p = 0.f;
      for (int d = 0; d < D4; ++d) {
        const float4 zv = z4r[d];
        const float4 ev = e4[(size_t)code * D4 + d];
        p = fmaf(zv.x, ev.x, p); p = fmaf(zv.y, ev.y, p);
        p = fmaf(zv.z, ev.z, p); p = fmaf(zv.w, ev.w, p);
      }
      bs = Ar - 2.0f * p;  // fl(A-2p), 2p exact
      bi = code;
    }
  } else {  // overflow fallback (rare): exact full scan
    for (int code = lane; code < KC; code += 64) {
      float p = 0.f;
      for (int d = 0; d < D4; ++d) {
        const float4 zv = z4r[d];
        const float4 ev = e4[(size_t)code * D4 + d];
        p = fmaf(zv.x, ev.x, p); p = fmaf(zv.y, ev.y, p);
        p = fmaf(zv.z, ev.z, p); p = fmaf(zv.w, ev.w, p);
      }
      const float s = Ar - 2.0f * p;
      if (s < bs || (s == bs && code < bi)) { bs = s; bi = code; }
    }
  }
#pragma unroll
  for (int off = 1; off < 64; off <<= 1) {
    const float os = __shfl_xor(bs, off, 64);
    const int oi = __shfl_xor(bi, off, 64);
    if (os < bs || (os == bs && oi < bi)) { bs = os; bi = oi; }
  }
  // all 64 lanes hold the winner; gather the output row
  const float4 v = e4[(size_t)bi * D4 + lane];
  ((float4*)out)[(size_t)row * D4 + lane] = v;
}

extern "C" void kernel_launch(void* const* d_in, const int* in_sizes, int n_in,
                              void* d_out, int out_size, void* d_ws, size_t ws_size,
                              hipStream_t stream) {
  const float* z = (const float*)d_in[0];    // [32768, 256] f32
  const float* emb = (const float*)d_in[1];  // [8192, 256] f32
  float* out = (float*)d_out;                // [32768, 256] f32

  char* wsb = (char*)d_ws;
  float* An = (float*)(wsb);                         // 128 KB
  int* cnt = (int*)(wsb + (128 << 10));              // 128 KB
  uint* rowmin = (uint*)(wsb + (256 << 10));         // 128 KB
  uint* list = (uint*)(wsb + (512 << 10));           // 32768*64*4B = 8 MB
  _Float16* z16 = (_Float16*)(wsb + (512 << 10) + (16 << 20));  // 16 MB
  _Float16* e16 = (_Float16*)(wsb + (512 << 10) + (32 << 20));  // 4 MB

  vq_znorm<<<NROWS / 256, 256, 0, stream>>>(z, An);
  vq_convert<<<2048, 256, 0, stream>>>(z, emb, z16, e16, cnt, rowmin);
  vq_gemm_filter<<<2048, 256, 0, stream>>>(z16, e16, An, rowmin, cnt, list);
  vq_recheck_gather<<<NROWS / 4, 256, 0, stream>>>(z, emb, An, cnt, list, out);
}

// Round 9
// 1238.035 us; speedup vs baseline: 1.0395x; 1.0395x over previous
//
#include <hip/hip_runtime.h>

#define NROWS 32768
#define KC 8192
#define DDIM 256
#define D4 64
#define CAP 128
#define DACC 2.0f          // acc-domain margin = 2/4096 = 4.88e-4 in score
#define MT 128
#define SEGC 1024
#define PAN 64
#define NPAN 16

typedef _Float16 half8 __attribute__((ext_vector_type(8)));
typedef float f32x4 __attribute__((ext_vector_type(4)));
typedef unsigned int uint;
typedef const __attribute__((address_space(1))) unsigned int* gptr_u32;
typedef __attribute__((address_space(3))) unsigned int* lptr_u32;

union H4 { ushort4 u; _Float16 h[4]; };

// fmax-reduce over each 16-lane group via DPP row_ror (pure VALU)
template <int CTRL>
__device__ __forceinline__ float rormax_step(float x) {
  const int v = __builtin_amdgcn_mov_dpp(__float_as_int(x), CTRL, 0xf, 0xf, true);
  return fmaxf(x, __int_as_float(v));
}
__device__ __forceinline__ float redmax16(float x) {
  x = rormax_step<0x121>(x);
  x = rormax_step<0x122>(x);
  x = rormax_step<0x124>(x);
  x = rormax_step<0x128>(x);
  return x;
}

// ---------------- kernel 1: bit-exact numpy pairwise row norm ----------------
__global__ __launch_bounds__(256) void vq_znorm(const float* __restrict__ z,
                                                float* __restrict__ An) {
#pragma clang fp contract(off)
  const int row = blockIdx.x * 256 + threadIdx.x;
  const float4* p4 = (const float4*)(z + (size_t)row * 256);
  float halves[2];
#pragma unroll
  for (int h = 0; h < 2; ++h) {
    float r[8];
    float4 a = p4[h * 32 + 0], b = p4[h * 32 + 1];
    r[0] = a.x * a.x; r[1] = a.y * a.y; r[2] = a.z * a.z; r[3] = a.w * a.w;
    r[4] = b.x * b.x; r[5] = b.y * b.y; r[6] = b.z * b.z; r[7] = b.w * b.w;
    for (int i = 1; i < 16; ++i) {  // 8-elem chunks in numpy pairwise order
      a = p4[h * 32 + i * 2];
      b = p4[h * 32 + i * 2 + 1];
      r[0] += a.x * a.x; r[1] += a.y * a.y; r[2] += a.z * a.z; r[3] += a.w * a.w;
      r[4] += b.x * b.x; r[5] += b.y * b.y; r[6] += b.z * b.z; r[7] += b.w * b.w;
    }
    halves[h] = ((r[0] + r[1]) + (r[2] + r[3])) + ((r[4] + r[5]) + (r[6] + r[7]));
  }
  An[row] = halves[0] + halves[1];
}

// ---------------- kernel 2: f32 -> f16 conversion (+ scale e by 2^13) + init ----------------
__global__ __launch_bounds__(256) void vq_convert(const float* __restrict__ z,
                                                  const float* __restrict__ emb,
                                                  _Float16* __restrict__ z16,
                                                  _Float16* __restrict__ e16,
                                                  int* __restrict__ cnt) {
  const int tid = blockIdx.x * 256 + threadIdx.x;  // 524288 threads
  const float4* z4 = (const float4*)z;
  const float4* e4 = (const float4*)emb;
  ushort4* z16u = (ushort4*)z16;
  ushort4* e16u = (ushort4*)e16;
#pragma unroll
  for (int t = 0; t < 4; ++t) {
    const int i = tid + t * 524288;
    const float4 v = z4[i];
    H4 o;
    o.h[0] = (_Float16)v.x; o.h[1] = (_Float16)v.y;
    o.h[2] = (_Float16)v.z; o.h[3] = (_Float16)v.w;
    z16u[i] = o.u;
  }
  {
    const int i = tid;  // 524288 = 8192*64
    const float4 v = e4[i];
    H4 o;
    o.h[0] = (_Float16)(v.x * 8192.0f); o.h[1] = (_Float16)(v.y * 8192.0f);
    o.h[2] = (_Float16)(v.z * 8192.0f); o.h[3] = (_Float16)(v.w * 8192.0f);
    e16u[i] = o.u;
  }
  if (tid < NROWS) cnt[tid] = 0;
}

// ---------------- kernel 3: pre-pass — segment-0 GEMM, rowthr = max acc over 1024 codes ----
// Identical af/bf/MFMA path as the main kernel -> bit-identical acc values.
__global__ __launch_bounds__(256) void vq_prepass(
    const _Float16* __restrict__ z16, const _Float16* __restrict__ e16,
    float* __restrict__ rowthr) {
  __shared__ _Float16 smem[32768];
  const int brow = blockIdx.x * MT;  // grid 256
  const int tid = threadIdx.x;
  const int lane = tid & 63, w = tid >> 6;
  const int l15 = lane & 15, l4 = lane >> 4;
  const int wr = w >> 1, wc = w & 1;
  const int wrow = wr * 64;

  // stage z tile (128x256 f16 = 64KB), pre-swizzled source
#pragma unroll
  for (int i = 0; i < 16; ++i) {
    const int c = tid + 256 * i;
    const int r = c >> 5, sl = (c & 31) ^ (r & 31);
    __builtin_amdgcn_global_load_lds(
        (gptr_u32)(z16 + (size_t)(brow + r) * DDIM + sl * 8),
        (lptr_u32)(smem + c * 8), 16, 0, 0);
  }
  __syncthreads();
  half8 af[4][8];
#pragma unroll
  for (int m = 0; m < 4; ++m) {
    const int row = wrow + m * 16 + l15;
#pragma unroll
    for (int k = 0; k < 8; ++k) {
      const int sl = (k * 4 + l4) ^ (row & 31);
      af[m][k] = *(const half8*)(smem + row * 256 + sl * 8);
    }
  }
  __syncthreads();

  float tm[4][4];
#pragma unroll
  for (int m = 0; m < 4; ++m)
#pragma unroll
    for (int r = 0; r < 4; ++r) tm[m][r] = -3.4e38f;

  // prologue: panel 0
#pragma unroll
  for (int i = 0; i < 8; ++i) {
    const int c = tid + 256 * i;
    const int r = c >> 5, sl = (c & 31) ^ (r & 31);
    __builtin_amdgcn_global_load_lds(
        (gptr_u32)(e16 + (size_t)r * DDIM + sl * 8),
        (lptr_u32)(smem + c * 8), 16, 0, 0);
  }
  __syncthreads();

  for (int p = 0; p < NPAN; ++p) {
    const int curoff = (p & 1) << 14;
    if (p + 1 < NPAN) {
      const int cb = (p + 1) * PAN;
      const int nxtoff = curoff ^ 16384;
#pragma unroll
      for (int i = 0; i < 8; ++i) {
        const int c = tid + 256 * i;
        const int r = c >> 5, sl = (c & 31) ^ (r & 31);
        __builtin_amdgcn_global_load_lds(
            (gptr_u32)(e16 + (size_t)(cb + r) * DDIM + sl * 8),
            (lptr_u32)(smem + nxtoff + c * 8), 16, 0, 0);
      }
    }
    f32x4 acc[4][2] = {{{0.f}}};
#pragma unroll
    for (int k = 0; k < 8; ++k) {
      half8 bf[2];
#pragma unroll
      for (int n = 0; n < 2; ++n) {
        const int crow = wc * 32 + n * 16 + l15;
        const int sl = (k * 4 + l4) ^ (crow & 31);
        bf[n] = *(const half8*)(smem + curoff + crow * 256 + sl * 8);
      }
#pragma unroll
      for (int m = 0; m < 4; ++m)
#pragma unroll
        for (int n = 0; n < 2; ++n)
          acc[m][n] = __builtin_amdgcn_mfma_f32_16x16x32_f16(af[m][k], bf[n], acc[m][n], 0, 0, 0);
    }
#pragma unroll
    for (int m = 0; m < 4; ++m)
#pragma unroll
      for (int r = 0; r < 4; ++r)
        tm[m][r] = fmaxf(tm[m][r], fmaxf(acc[m][0][r], acc[m][1][r]));
    __syncthreads();
  }
  // reduce across 16 lanes and across the 2 wc-waves (via LDS), then store
  __shared__ float red[2][128];  // [wc][row-in-tile]
#pragma unroll
  for (int m = 0; m < 4; ++m)
#pragma unroll
    for (int r = 0; r < 4; ++r) {
      const float mx = redmax16(tm[m][r]);
      if (l15 == 0) red[wc][wrow + m * 16 + l4 * 4 + r] = mx;
    }
  __syncthreads();
  // 128 rows, 256 threads: thread t<128 finalizes row t
  if (tid < 128) rowthr[brow + tid] = fmaxf(red[0][tid], red[1][tid]);
}

// ---------------- kernel 4: main z-stationary f16 MFMA GEMM + constant-threshold filter ----
// grid 2048 = 256 M-tiles x 8 segments; seg = bid&7. Epilogue: 32 compares + rare appends.
__global__ __launch_bounds__(256) void vq_gemm_filter(
    const _Float16* __restrict__ z16, const _Float16* __restrict__ e16,
    const float* __restrict__ rowthr, int* __restrict__ cnt,
    uint* __restrict__ list) {
  __shared__ _Float16 smem[32768];
  const int bid = blockIdx.x;
  const int seg = bid & 7, mIdx = bid >> 3;
  const int brow = mIdx * MT;
  const int c0seg = seg * SEGC;
  const int tid = threadIdx.x;
  const int lane = tid & 63, w = tid >> 6;
  const int l15 = lane & 15, l4 = lane >> 4;
  const int wr = w >> 1, wc = w & 1;
  const int wrow = wr * 64;

#pragma unroll
  for (int i = 0; i < 16; ++i) {
    const int c = tid + 256 * i;
    const int r = c >> 5, sl = (c & 31) ^ (r & 31);
    __builtin_amdgcn_global_load_lds(
        (gptr_u32)(z16 + (size_t)(brow + r) * DDIM + sl * 8),
        (lptr_u32)(smem + c * 8), 16, 0, 0);
  }
  __syncthreads();
  half8 af[4][8];
#pragma unroll
  for (int m = 0; m < 4; ++m) {
    const int row = wrow + m * 16 + l15;
#pragma unroll
    for (int k = 0; k < 8; ++k) {
      const int sl = (k * 4 + l4) ^ (row & 31);
      af[m][k] = *(const half8*)(smem + row * 256 + sl * 8);
    }
  }
  __syncthreads();

  // fixed acc-domain threshold (score-min superset guaranteed by DACC margin)
  float Lthr[4][4];
#pragma unroll
  for (int m = 0; m < 4; ++m)
#pragma unroll
    for (int r = 0; r < 4; ++r)
      Lthr[m][r] = rowthr[brow + wrow + m * 16 + l4 * 4 + r] - DACC;

  // prologue: panel 0
#pragma unroll
  for (int i = 0; i < 8; ++i) {
    const int c = tid + 256 * i;
    const int r = c >> 5, sl = (c & 31) ^ (r & 31);
    __builtin_amdgcn_global_load_lds(
        (gptr_u32)(e16 + (size_t)(c0seg + r) * DDIM + sl * 8),
        (lptr_u32)(smem + c * 8), 16, 0, 0);
  }
  __syncthreads();

  for (int p = 0; p < NPAN; ++p) {
    const int curoff = (p & 1) << 14;
    if (p + 1 < NPAN) {
      const int cb = c0seg + (p + 1) * PAN;
      const int nxtoff = curoff ^ 16384;
#pragma unroll
      for (int i = 0; i < 8; ++i) {
        const int c = tid + 256 * i;
        const int r = c >> 5, sl = (c & 31) ^ (r & 31);
        __builtin_amdgcn_global_load_lds(
            (gptr_u32)(e16 + (size_t)(cb + r) * DDIM + sl * 8),
            (lptr_u32)(smem + nxtoff + c * 8), 16, 0, 0);
      }
    }
    f32x4 acc[4][2] = {{{0.f}}};
#pragma unroll
    for (int k = 0; k < 8; ++k) {
      half8 bf[2];
#pragma unroll
      for (int n = 0; n < 2; ++n) {
        const int crow = wc * 32 + n * 16 + l15;
        const int sl = (k * 4 + l4) ^ (crow & 31);
        bf[n] = *(const half8*)(smem + curoff + crow * 256 + sl * 8);
      }
#pragma unroll
      for (int m = 0; m < 4; ++m)
#pragma unroll
        for (int n = 0; n < 2; ++n)
          acc[m][n] = __builtin_amdgcn_mfma_f32_16x16x32_f16(af[m][k], bf[n], acc[m][n], 0, 0, 0);
    }
    // epilogue: 32 compares, rare appends
#pragma unroll
    for (int m = 0; m < 4; ++m)
#pragma unroll
      for (int n = 0; n < 2; ++n)
#pragma unroll
        for (int r = 0; r < 4; ++r) {
          if (acc[m][n][r] >= Lthr[m][r]) {
            const int row = brow + wrow + m * 16 + l4 * 4 + r;
            const int code = c0seg + p * PAN + wc * 32 + n * 16 + l15;
            const int pos = atomicAdd(cnt + row, 1);
            if (pos < CAP) list[(size_t)row * CAP + pos] = (uint)code;
          }
        }
    __syncthreads();
  }
}

// ---------------- kernel 5: exact recheck (bit-exact np chain) + gather ----------------
__global__ __launch_bounds__(256) void vq_recheck_gather(
    const float* __restrict__ z, const float* __restrict__ emb,
    const float* __restrict__ An, const int* __restrict__ cnt,
    const uint* __restrict__ list, float* __restrict__ out) {
  const int row = blockIdx.x * 4 + (threadIdx.x >> 6);
  const int lane = threadIdx.x & 63;
  const int nc = cnt[row];
  const float Ar = An[row];
  const float4* z4r = (const float4*)z + (size_t)row * D4;
  const float4* e4 = (const float4*)emb;
  float bs = 3.4e38f;
  int bi = 0x7fffffff;
  if (nc <= CAP) {
    for (int c = lane; c < nc; c += 64) {
      const int code = (int)list[(size_t)row * CAP + c];
      float p = 0.f;
      for (int d = 0; d < D4; ++d) {
        const float4 zv = z4r[d];
        const float4 ev = e4[(size_t)code * D4 + d];
        p = fmaf(zv.x, ev.x, p); p = fmaf(zv.y, ev.y, p);
        p = fmaf(zv.z, ev.z, p); p = fmaf(zv.w, ev.w, p);
      }
      const float s = Ar - 2.0f * p;  // fl(A-2p), 2p exact
      if (s < bs || (s == bs && code < bi)) { bs = s; bi = code; }
    }
  } else {  // overflow fallback (essentially never): exact full scan
    for (int code = lane; code < KC; code += 64) {
      float p = 0.f;
      for (int d = 0; d < D4; ++d) {
        const float4 zv = z4r[d];
        const float4 ev = e4[(size_t)code * D4 + d];
        p = fmaf(zv.x, ev.x, p); p = fmaf(zv.y, ev.y, p);
        p = fmaf(zv.z, ev.z, p); p = fmaf(zv.w, ev.w, p);
      }
      const float s = Ar - 2.0f * p;
      if (s < bs || (s == bs && code < bi)) { bs = s; bi = code; }
    }
  }
#pragma unroll
  for (int off = 1; off < 64; off <<= 1) {
    const float os = __shfl_xor(bs, off, 64);
    const int oi = __shfl_xor(bi, off, 64);
    if (os < bs || (os == bs && oi < bi)) { bs = os; bi = oi; }
  }
  const float4 v = e4[(size_t)bi * D4 + lane];
  ((float4*)out)[(size_t)row * D4 + lane] = v;
}

extern "C" void kernel_launch(void* const* d_in, const int* in_sizes, int n_in,
                              void* d_out, int out_size, void* d_ws, size_t ws_size,
                              hipStream_t stream) {
  const float* z = (const float*)d_in[0];    // [32768, 256] f32
  const float* emb = (const float*)d_in[1];  // [8192, 256] f32
  float* out = (float*)d_out;                // [32768, 256] f32

  char* wsb = (char*)d_ws;
  float* An = (float*)(wsb);                         // 128 KB
  int* cnt = (int*)(wsb + (128 << 10));              // 128 KB
  float* rowthr = (float*)(wsb + (256 << 10));       // 128 KB
  uint* list = (uint*)(wsb + (512 << 10));           // 32768*128*4B = 16 MB
  _Float16* z16 = (_Float16*)(wsb + (512 << 10) + (16 << 20));  // 16 MB
  _Float16* e16 = (_Float16*)(wsb + (512 << 10) + (32 << 20));  // 4 MB

  vq_znorm<<<NROWS / 256, 256, 0, stream>>>(z, An);
  vq_convert<<<2048, 256, 0, stream>>>(z, emb, z16, e16, cnt);
  vq_prepass<<<NROWS / MT, 256, 0, stream>>>(z16, e16, rowthr);
  vq_gemm_filter<<<2048, 256, 0, stream>>>(z16, e16, rowthr, cnt, list);
  vq_recheck_gather<<<NROWS / 4, 256, 0, stream>>>(z, emb, An, cnt, list, out);
}

// Round 10
// 1039.339 us; speedup vs baseline: 1.2382x; 1.1912x over previous
//
#include <hip/hip_runtime.h>

#define NROWS 32768
#define KC 8192
#define DDIM 256
#define D4 64
#define CAP 128
#define DACC 2.0f          // acc-domain margin = 2/4096 = 4.88e-4 in score
#define MT 128
#define SEGC 1024
#define PAN 64
#define NPAN 16

typedef _Float16 half8 __attribute__((ext_vector_type(8)));
typedef float f32x4 __attribute__((ext_vector_type(4)));
typedef unsigned int uint;
typedef const __attribute__((address_space(1))) unsigned int* gptr_u32;
typedef __attribute__((address_space(3))) unsigned int* lptr_u32;

union H4 { ushort4 u; _Float16 h[4]; };

// fmax-reduce over each 16-lane group via DPP row_ror (pure VALU)
template <int CTRL>
__device__ __forceinline__ float rormax_step(float x) {
  const int v = __builtin_amdgcn_mov_dpp(__float_as_int(x), CTRL, 0xf, 0xf, true);
  return fmaxf(x, __int_as_float(v));
}
__device__ __forceinline__ float redmax16(float x) {
  x = rormax_step<0x121>(x);
  x = rormax_step<0x122>(x);
  x = rormax_step<0x124>(x);
  x = rormax_step<0x128>(x);
  return x;
}

// ---------------- kernel 1: bit-exact numpy pairwise row norm ----------------
__global__ __launch_bounds__(256) void vq_znorm(const float* __restrict__ z,
                                                float* __restrict__ An) {
#pragma clang fp contract(off)
  const int row = blockIdx.x * 256 + threadIdx.x;
  const float4* p4 = (const float4*)(z + (size_t)row * 256);
  float halves[2];
#pragma unroll
  for (int h = 0; h < 2; ++h) {
    float r[8];
    float4 a = p4[h * 32 + 0], b = p4[h * 32 + 1];
    r[0] = a.x * a.x; r[1] = a.y * a.y; r[2] = a.z * a.z; r[3] = a.w * a.w;
    r[4] = b.x * b.x; r[5] = b.y * b.y; r[6] = b.z * b.z; r[7] = b.w * b.w;
    for (int i = 1; i < 16; ++i) {  // 8-elem chunks in numpy pairwise order
      a = p4[h * 32 + i * 2];
      b = p4[h * 32 + i * 2 + 1];
      r[0] += a.x * a.x; r[1] += a.y * a.y; r[2] += a.z * a.z; r[3] += a.w * a.w;
      r[4] += b.x * b.x; r[5] += b.y * b.y; r[6] += b.z * b.z; r[7] += b.w * b.w;
    }
    halves[h] = ((r[0] + r[1]) + (r[2] + r[3])) + ((r[4] + r[5]) + (r[6] + r[7]));
  }
  An[row] = halves[0] + halves[1];
}

// ---------------- kernel 2: f32 -> f16 conversion (+ scale e by 2^13) + init ----------------
__global__ __launch_bounds__(256) void vq_convert(const float* __restrict__ z,
                                                  const float* __restrict__ emb,
                                                  _Float16* __restrict__ z16,
                                                  _Float16* __restrict__ e16,
                                                  int* __restrict__ cnt) {
  const int tid = blockIdx.x * 256 + threadIdx.x;  // 524288 threads
  const float4* z4 = (const float4*)z;
  const float4* e4 = (const float4*)emb;
  ushort4* z16u = (ushort4*)z16;
  ushort4* e16u = (ushort4*)e16;
#pragma unroll
  for (int t = 0; t < 4; ++t) {
    const int i = tid + t * 524288;
    const float4 v = z4[i];
    H4 o;
    o.h[0] = (_Float16)v.x; o.h[1] = (_Float16)v.y;
    o.h[2] = (_Float16)v.z; o.h[3] = (_Float16)v.w;
    z16u[i] = o.u;
  }
  {
    const int i = tid;  // 524288 = 8192*64
    const float4 v = e4[i];
    H4 o;
    o.h[0] = (_Float16)(v.x * 8192.0f); o.h[1] = (_Float16)(v.y * 8192.0f);
    o.h[2] = (_Float16)(v.z * 8192.0f); o.h[3] = (_Float16)(v.w * 8192.0f);
    e16u[i] = o.u;
  }
  if (tid < NROWS) cnt[tid] = 0;
}

// ---------------- kernel 3: pre-pass — segment-0 GEMM, rowthr = max acc over 1024 codes ----
__global__ __launch_bounds__(256) void vq_prepass(
    const _Float16* __restrict__ z16, const _Float16* __restrict__ e16,
    float* __restrict__ rowthr) {
  __shared__ _Float16 smem[32768];
  const int brow = blockIdx.x * MT;  // grid 256
  const int tid = threadIdx.x;
  const int lane = tid & 63, w = tid >> 6;
  const int l15 = lane & 15, l4 = lane >> 4;
  const int wr = w >> 1, wc = w & 1;
  const int wrow = wr * 64;

#pragma unroll
  for (int i = 0; i < 16; ++i) {
    const int c = tid + 256 * i;
    const int r = c >> 5, sl = (c & 31) ^ (r & 31);
    __builtin_amdgcn_global_load_lds(
        (gptr_u32)(z16 + (size_t)(brow + r) * DDIM + sl * 8),
        (lptr_u32)(smem + c * 8), 16, 0, 0);
  }
  __syncthreads();
  half8 af[4][8];
#pragma unroll
  for (int m = 0; m < 4; ++m) {
    const int row = wrow + m * 16 + l15;
#pragma unroll
    for (int k = 0; k < 8; ++k) {
      const int sl = (k * 4 + l4) ^ (row & 31);
      af[m][k] = *(const half8*)(smem + row * 256 + sl * 8);
    }
  }
  __syncthreads();

  float tm[4][4];
#pragma unroll
  for (int m = 0; m < 4; ++m)
#pragma unroll
    for (int r = 0; r < 4; ++r) tm[m][r] = -3.4e38f;

#pragma unroll
  for (int i = 0; i < 8; ++i) {
    const int c = tid + 256 * i;
    const int r = c >> 5, sl = (c & 31) ^ (r & 31);
    __builtin_amdgcn_global_load_lds(
        (gptr_u32)(e16 + (size_t)r * DDIM + sl * 8),
        (lptr_u32)(smem + c * 8), 16, 0, 0);
  }
  __syncthreads();

  for (int p = 0; p < NPAN; ++p) {
    const int curoff = (p & 1) << 14;
    if (p + 1 < NPAN) {
      const int cb = (p + 1) * PAN;
      const int nxtoff = curoff ^ 16384;
#pragma unroll
      for (int i = 0; i < 8; ++i) {
        const int c = tid + 256 * i;
        const int r = c >> 5, sl = (c & 31) ^ (r & 31);
        __builtin_amdgcn_global_load_lds(
            (gptr_u32)(e16 + (size_t)(cb + r) * DDIM + sl * 8),
            (lptr_u32)(smem + nxtoff + c * 8), 16, 0, 0);
      }
    }
    f32x4 acc[4][2] = {{{0.f}}};
#pragma unroll
    for (int k = 0; k < 8; ++k) {
      half8 bf[2];
#pragma unroll
      for (int n = 0; n < 2; ++n) {
        const int crow = wc * 32 + n * 16 + l15;
        const int sl = (k * 4 + l4) ^ (crow & 31);
        bf[n] = *(const half8*)(smem + curoff + crow * 256 + sl * 8);
      }
#pragma unroll
      for (int m = 0; m < 4; ++m)
#pragma unroll
        for (int n = 0; n < 2; ++n)
          acc[m][n] = __builtin_amdgcn_mfma_f32_16x16x32_f16(af[m][k], bf[n], acc[m][n], 0, 0, 0);
    }
#pragma unroll
    for (int m = 0; m < 4; ++m)
#pragma unroll
      for (int r = 0; r < 4; ++r)
        tm[m][r] = fmaxf(tm[m][r], fmaxf(acc[m][0][r], acc[m][1][r]));
    __syncthreads();
  }
  __shared__ float red[2][128];  // [wc][row-in-tile]
#pragma unroll
  for (int m = 0; m < 4; ++m)
#pragma unroll
    for (int r = 0; r < 4; ++r) {
      const float mx = redmax16(tm[m][r]);
      if (l15 == 0) red[wc][wrow + m * 16 + l4 * 4 + r] = mx;
    }
  __syncthreads();
  if (tid < 128) rowthr[brow + tid] = fmaxf(red[0][tid], red[1][tid]);
}

// ---------------- kernel 4: main z-stationary f16 MFMA GEMM + constant-threshold filter ----
__global__ __launch_bounds__(256) void vq_gemm_filter(
    const _Float16* __restrict__ z16, const _Float16* __restrict__ e16,
    const float* __restrict__ rowthr, int* __restrict__ cnt,
    uint* __restrict__ list) {
  __shared__ _Float16 smem[32768];
  const int bid = blockIdx.x;
  const int seg = bid & 7, mIdx = bid >> 3;
  const int brow = mIdx * MT;
  const int c0seg = seg * SEGC;
  const int tid = threadIdx.x;
  const int lane = tid & 63, w = tid >> 6;
  const int l15 = lane & 15, l4 = lane >> 4;
  const int wr = w >> 1, wc = w & 1;
  const int wrow = wr * 64;

#pragma unroll
  for (int i = 0; i < 16; ++i) {
    const int c = tid + 256 * i;
    const int r = c >> 5, sl = (c & 31) ^ (r & 31);
    __builtin_amdgcn_global_load_lds(
        (gptr_u32)(z16 + (size_t)(brow + r) * DDIM + sl * 8),
        (lptr_u32)(smem + c * 8), 16, 0, 0);
  }
  __syncthreads();
  half8 af[4][8];
#pragma unroll
  for (int m = 0; m < 4; ++m) {
    const int row = wrow + m * 16 + l15;
#pragma unroll
    for (int k = 0; k < 8; ++k) {
      const int sl = (k * 4 + l4) ^ (row & 31);
      af[m][k] = *(const half8*)(smem + row * 256 + sl * 8);
    }
  }
  __syncthreads();

  float Lthr[4][4];
#pragma unroll
  for (int m = 0; m < 4; ++m)
#pragma unroll
    for (int r = 0; r < 4; ++r)
      Lthr[m][r] = rowthr[brow + wrow + m * 16 + l4 * 4 + r] - DACC;

#pragma unroll
  for (int i = 0; i < 8; ++i) {
    const int c = tid + 256 * i;
    const int r = c >> 5, sl = (c & 31) ^ (r & 31);
    __builtin_amdgcn_global_load_lds(
        (gptr_u32)(e16 + (size_t)(c0seg + r) * DDIM + sl * 8),
        (lptr_u32)(smem + c * 8), 16, 0, 0);
  }
  __syncthreads();

  for (int p = 0; p < NPAN; ++p) {
    const int curoff = (p & 1) << 14;
    if (p + 1 < NPAN) {
      const int cb = c0seg + (p + 1) * PAN;
      const int nxtoff = curoff ^ 16384;
#pragma unroll
      for (int i = 0; i < 8; ++i) {
        const int c = tid + 256 * i;
        const int r = c >> 5, sl = (c & 31) ^ (r & 31);
        __builtin_amdgcn_global_load_lds(
            (gptr_u32)(e16 + (size_t)(cb + r) * DDIM + sl * 8),
            (lptr_u32)(smem + nxtoff + c * 8), 16, 0, 0);
      }
    }
    f32x4 acc[4][2] = {{{0.f}}};
#pragma unroll
    for (int k = 0; k < 8; ++k) {
      half8 bf[2];
#pragma unroll
      for (int n = 0; n < 2; ++n) {
        const int crow = wc * 32 + n * 16 + l15;
        const int sl = (k * 4 + l4) ^ (crow & 31);
        bf[n] = *(const half8*)(smem + curoff + crow * 256 + sl * 8);
      }
#pragma unroll
      for (int m = 0; m < 4; ++m)
#pragma unroll
        for (int n = 0; n < 2; ++n)
          acc[m][n] = __builtin_amdgcn_mfma_f32_16x16x32_f16(af[m][k], bf[n], acc[m][n], 0, 0, 0);
    }
#pragma unroll
    for (int m = 0; m < 4; ++m)
#pragma unroll
      for (int n = 0; n < 2; ++n)
#pragma unroll
        for (int r = 0; r < 4; ++r) {
          if (acc[m][n][r] >= Lthr[m][r]) {
            const int row = brow + wrow + m * 16 + l4 * 4 + r;
            const int code = c0seg + p * PAN + wc * 32 + n * 16 + l15;
            const int pos = atomicAdd(cnt + row, 1);
            if (pos < CAP) list[(size_t)row * CAP + pos] = (uint)code;
          }
        }
    __syncthreads();
  }
}

// ---------------- kernel 5: exact recheck (bit-exact np chain) + gather ----------------
// 4 waves/block, 1 row per wave. z row staged in LDS (broadcast reads);
// emb row prefetched in 8 register chunks of 8 float4 -> loads hide under fma chain.
__global__ __launch_bounds__(256) void vq_recheck_gather(
    const float* __restrict__ z, const float* __restrict__ emb,
    const float* __restrict__ An, const int* __restrict__ cnt,
    const uint* __restrict__ list, float* __restrict__ out) {
  __shared__ float4 zsh[4][64];
  const int wv = threadIdx.x >> 6;
  const int lane = threadIdx.x & 63;
  const int row = blockIdx.x * 4 + wv;
  const float4* e4 = (const float4*)emb;

  // stage z row (coalesced 1KB per wave)
  zsh[wv][lane] = ((const float4*)z)[(size_t)row * D4 + lane];
  __syncthreads();

  const int nc = cnt[row];
  const float Ar = An[row];
  float bs = 3.4e38f;
  int bi = 0x7fffffff;

  if (nc <= CAP) {
    for (int c = lane; c < nc; c += 64) {  // one pass: nc <= CAP=128, lane covers <=2
      const int code = (int)list[(size_t)row * CAP + c];
      const float4* ep = e4 + (size_t)code * D4;
      float p = 0.f;
#pragma unroll
      for (int ch = 0; ch < 8; ++ch) {
        float4 ev[8];
#pragma unroll
        for (int j = 0; j < 8; ++j) ev[j] = ep[ch * 8 + j];  // batched loads
#pragma unroll
        for (int j = 0; j < 8; ++j) {  // exact ascending-d fma chain
          const float4 zv = zsh[wv][ch * 8 + j];
          p = fmaf(zv.x, ev[j].x, p); p = fmaf(zv.y, ev[j].y, p);
          p = fmaf(zv.z, ev[j].z, p); p = fmaf(zv.w, ev[j].w, p);
        }
      }
      const float s = Ar - 2.0f * p;  // fl(A-2p), 2p exact
      if (s < bs || (s == bs && code < bi)) { bs = s; bi = code; }
    }
  } else {  // overflow fallback (essentially never): exact full scan
    for (int code = lane; code < KC; code += 64) {
      const float4* ep = e4 + (size_t)code * D4;
      float p = 0.f;
#pragma unroll 2
      for (int ch = 0; ch < 8; ++ch) {
        float4 ev[8];
#pragma unroll
        for (int j = 0; j < 8; ++j) ev[j] = ep[ch * 8 + j];
#pragma unroll
        for (int j = 0; j < 8; ++j) {
          const float4 zv = zsh[wv][ch * 8 + j];
          p = fmaf(zv.x, ev[j].x, p); p = fmaf(zv.y, ev[j].y, p);
          p = fmaf(zv.z, ev[j].z, p); p = fmaf(zv.w, ev[j].w, p);
        }
      }
      const float s = Ar - 2.0f * p;
      if (s < bs || (s == bs && code < bi)) { bs = s; bi = code; }
    }
  }
#pragma unroll
  for (int off = 1; off < 64; off <<= 1) {
    const float os = __shfl_xor(bs, off, 64);
    const int oi = __shfl_xor(bi, off, 64);
    if (os < bs || (os == bs && oi < bi)) { bs = os; bi = oi; }
  }
  // all 64 lanes hold the winner; gather the output row (coalesced 1KB)
  const float4 v = e4[(size_t)bi * D4 + lane];
  ((float4*)out)[(size_t)row * D4 + lane] = v;
}

extern "C" void kernel_launch(void* const* d_in, const int* in_sizes, int n_in,
                              void* d_out, int out_size, void* d_ws, size_t ws_size,
                              hipStream_t stream) {
  const float* z = (const float*)d_in[0];    // [32768, 256] f32
  const float* emb = (const float*)d_in[1];  // [8192, 256] f32
  float* out = (float*)d_out;                // [32768, 256] f32

  char* wsb = (char*)d_ws;
  float* An = (float*)(wsb);                         // 128 KB
  int* cnt = (int*)(wsb + (128 << 10));              // 128 KB
  float* rowthr = (float*)(wsb + (256 << 10));       // 128 KB
  uint* list = (uint*)(wsb + (512 << 10));           // 32768*128*4B = 16 MB
  _Float16* z16 = (_Float16*)(wsb + (512 << 10) + (16 << 20));  // 16 MB
  _Float16* e16 = (_Float16*)(wsb + (512 << 10) + (32 << 20));  // 4 MB

  vq_znorm<<<NROWS / 256, 256, 0, stream>>>(z, An);
  vq_convert<<<2048, 256, 0, stream>>>(z, emb, z16, e16, cnt);
  vq_prepass<<<NROWS / MT, 256, 0, stream>>>(z16, e16, rowthr);
  vq_gemm_filter<<<2048, 256, 0, stream>>>(z16, e16, rowthr, cnt, list);
  vq_recheck_gather<<<NROWS / 4, 256, 0, stream>>>(z, emb, An, cnt, list, out);
}

// Round 11
// 690.713 us; speedup vs baseline: 1.8632x; 1.5047x over previous
//
#include <hip/hip_runtime.h>

#define NROWS 32768
#define KC 8192
#define DDIM 256
#define D4 64
#define CAP 128
#define DACC 2.0f          // acc-domain margin = 2/4096 = 4.88e-4 in score units
#define MT 128
#define SEGC 1024
#define PAN 64
#define NPAN 16
#define PRESEG 2           // prepass samples 2 segments = 2048 codes

typedef _Float16 half8 __attribute__((ext_vector_type(8)));
typedef float f32x4 __attribute__((ext_vector_type(4)));
typedef unsigned int uint;

union H4 { ushort4 u; _Float16 h[4]; };

// fmax-reduce over each 16-lane group via DPP row_ror (pure VALU)
template <int CTRL>
__device__ __forceinline__ float rormax_step(float x) {
  const int v = __builtin_amdgcn_mov_dpp(__float_as_int(x), CTRL, 0xf, 0xf, true);
  return fmaxf(x, __int_as_float(v));
}
__device__ __forceinline__ float redmax16(float x) {
  x = rormax_step<0x121>(x);
  x = rormax_step<0x122>(x);
  x = rormax_step<0x124>(x);
  x = rormax_step<0x128>(x);
  return x;
}

// ---------------- kernel 1: bit-exact numpy pairwise row norm ----------------
__global__ __launch_bounds__(256) void vq_znorm(const float* __restrict__ z,
                                                float* __restrict__ An) {
#pragma clang fp contract(off)
  const int row = blockIdx.x * 256 + threadIdx.x;
  const float4* p4 = (const float4*)(z + (size_t)row * 256);
  float halves[2];
#pragma unroll
  for (int h = 0; h < 2; ++h) {
    float r[8];
    float4 a = p4[h * 32 + 0], b = p4[h * 32 + 1];
    r[0] = a.x * a.x; r[1] = a.y * a.y; r[2] = a.z * a.z; r[3] = a.w * a.w;
    r[4] = b.x * b.x; r[5] = b.y * b.y; r[6] = b.z * b.z; r[7] = b.w * b.w;
    for (int i = 1; i < 16; ++i) {  // 8-elem chunks in numpy pairwise order
      a = p4[h * 32 + i * 2];
      b = p4[h * 32 + i * 2 + 1];
      r[0] += a.x * a.x; r[1] += a.y * a.y; r[2] += a.z * a.z; r[3] += a.w * a.w;
      r[4] += b.x * b.x; r[5] += b.y * b.y; r[6] += b.z * b.z; r[7] += b.w * b.w;
    }
    halves[h] = ((r[0] + r[1]) + (r[2] + r[3])) + ((r[4] + r[5]) + (r[6] + r[7]));
  }
  An[row] = halves[0] + halves[1];
}

// ---------------- kernel 2: f32 -> f16 conversion (+ scale e by 2^13) + init ----------------
__global__ __launch_bounds__(256) void vq_convert(const float* __restrict__ z,
                                                  const float* __restrict__ emb,
                                                  _Float16* __restrict__ z16,
                                                  _Float16* __restrict__ e16,
                                                  int* __restrict__ cnt) {
  const int tid = blockIdx.x * 256 + threadIdx.x;  // 524288 threads
  const float4* z4 = (const float4*)z;
  const float4* e4 = (const float4*)emb;
  ushort4* z16u = (ushort4*)z16;
  ushort4* e16u = (ushort4*)e16;
#pragma unroll
  for (int t = 0; t < 4; ++t) {
    const int i = tid + t * 524288;
    const float4 v = z4[i];
    H4 o;
    o.h[0] = (_Float16)v.x; o.h[1] = (_Float16)v.y;
    o.h[2] = (_Float16)v.z; o.h[3] = (_Float16)v.w;
    z16u[i] = o.u;
  }
  {
    const int i = tid;  // 524288 = 8192*64
    const float4 v = e4[i];
    H4 o;
    o.h[0] = (_Float16)(v.x * 8192.0f); o.h[1] = (_Float16)(v.y * 8192.0f);
    o.h[2] = (_Float16)(v.z * 8192.0f); o.h[3] = (_Float16)(v.w * 8192.0f);
    e16u[i] = o.u;
  }
  if (tid < NROWS) cnt[tid] = 0;
}

// ---------------- kernel 3: pre-pass — codes 0..2047, rowthr = max acc ----------------
// Barrier-free streaming GEMM path identical to the main kernel -> bit-identical acc.
__global__ __launch_bounds__(256, 2) void vq_prepass(
    const _Float16* __restrict__ z16, const _Float16* __restrict__ e16,
    float* __restrict__ rowthr) {
  const int brow = blockIdx.x * MT;  // grid 256
  const int tid = threadIdx.x;
  const int lane = tid & 63, w = tid >> 6;
  const int l15 = lane & 15, l4 = lane >> 4;
  const int wr = w >> 1, wc = w & 1;
  const int wrow = wr * 64;

  half8 af[4][8];
#pragma unroll
  for (int m = 0; m < 4; ++m)
#pragma unroll
    for (int k = 0; k < 8; ++k)
      af[m][k] = *(const half8*)(z16 + (size_t)(brow + wrow + m * 16 + l15) * DDIM + k * 32 + l4 * 8);

  float tm[4][4];
#pragma unroll
  for (int m = 0; m < 4; ++m)
#pragma unroll
    for (int r = 0; r < 4; ++r) tm[m][r] = -3.4e38f;

  const _Float16* eb0 = e16 + (size_t)(wc * 32 + l15) * DDIM + l4 * 8;
  const _Float16* eb1 = eb0 + 16 * DDIM;

  half8 b0 = *(const half8*)(eb0);
  half8 b1 = *(const half8*)(eb1);
  for (int p = 0; p < PRESEG * NPAN; ++p) {
    f32x4 acc[4][2] = {{{0.f}}};
#pragma unroll
    for (int k = 0; k < 8; ++k) {
      const half8 u0 = b0, u1 = b1;
      if (k < 7) {
        b0 = *(const half8*)(eb0 + (k + 1) * 32);
        b1 = *(const half8*)(eb1 + (k + 1) * 32);
      } else {
        eb0 += PAN * DDIM; eb1 += PAN * DDIM;
        if (p < PRESEG * NPAN - 1) {
          b0 = *(const half8*)(eb0);
          b1 = *(const half8*)(eb1);
        }
      }
#pragma unroll
      for (int m = 0; m < 4; ++m)
        acc[m][0] = __builtin_amdgcn_mfma_f32_16x16x32_f16(af[m][k], u0, acc[m][0], 0, 0, 0);
#pragma unroll
      for (int m = 0; m < 4; ++m)
        acc[m][1] = __builtin_amdgcn_mfma_f32_16x16x32_f16(af[m][k], u1, acc[m][1], 0, 0, 0);
    }
#pragma unroll
    for (int m = 0; m < 4; ++m)
#pragma unroll
      for (int r = 0; r < 4; ++r)
        tm[m][r] = fmaxf(tm[m][r], fmaxf(acc[m][0][r], acc[m][1][r]));
  }

  __shared__ float red[2][128];  // [wc][row-in-tile]
#pragma unroll
  for (int m = 0; m < 4; ++m)
#pragma unroll
    for (int r = 0; r < 4; ++r) {
      const float mx = redmax16(tm[m][r]);
      if (l15 == 0) red[wc][wrow + m * 16 + l4 * 4 + r] = mx;
    }
  __syncthreads();
  if (tid < 128) rowthr[brow + tid] = fmaxf(red[0][tid], red[1][tid]);
}

// ---------------- kernel 4: barrier-free z-stationary GEMM + constant-threshold filter ----
// grid 2048 = 256 M-tiles x 8 segments; seg = bid&7 (== XCD id -> e-segment L2-hot).
// No LDS, no __syncthreads. af[4][8] register-resident; bf streamed from L2 with
// 1-k lookahead; next panel's k0 loads issued under the epilogue.
__global__ __launch_bounds__(256, 2) void vq_gemm_filter(
    const _Float16* __restrict__ z16, const _Float16* __restrict__ e16,
    const float* __restrict__ rowthr, int* __restrict__ cnt,
    uint* __restrict__ list) {
  const int bid = blockIdx.x;
  const int seg = bid & 7, mIdx = bid >> 3;
  const int brow = mIdx * MT;
  const int c0seg = seg * SEGC;
  const int tid = threadIdx.x;
  const int lane = tid & 63, w = tid >> 6;
  const int l15 = lane & 15, l4 = lane >> 4;
  const int wr = w >> 1, wc = w & 1;
  const int wrow = wr * 64;

  half8 af[4][8];
#pragma unroll
  for (int m = 0; m < 4; ++m)
#pragma unroll
    for (int k = 0; k < 8; ++k)
      af[m][k] = *(const half8*)(z16 + (size_t)(brow + wrow + m * 16 + l15) * DDIM + k * 32 + l4 * 8);

  float Lthr[4][4];
#pragma unroll
  for (int m = 0; m < 4; ++m)
#pragma unroll
    for (int r = 0; r < 4; ++r)
      Lthr[m][r] = rowthr[brow + wrow + m * 16 + l4 * 4 + r] - DACC;

  const _Float16* eb0 = e16 + (size_t)(c0seg + wc * 32 + l15) * DDIM + l4 * 8;
  const _Float16* eb1 = eb0 + 16 * DDIM;

  half8 b0 = *(const half8*)(eb0);
  half8 b1 = *(const half8*)(eb1);
  for (int p = 0; p < NPAN; ++p) {
    f32x4 acc[4][2] = {{{0.f}}};
#pragma unroll
    for (int k = 0; k < 8; ++k) {
      const half8 u0 = b0, u1 = b1;
      if (k < 7) {
        b0 = *(const half8*)(eb0 + (k + 1) * 32);
        b1 = *(const half8*)(eb1 + (k + 1) * 32);
      } else {
        eb0 += PAN * DDIM; eb1 += PAN * DDIM;
        if (p < NPAN - 1) {  // next panel's k0 flies under the epilogue
          b0 = *(const half8*)(eb0);
          b1 = *(const half8*)(eb1);
        }
      }
#pragma unroll
      for (int m = 0; m < 4; ++m)
        acc[m][0] = __builtin_amdgcn_mfma_f32_16x16x32_f16(af[m][k], u0, acc[m][0], 0, 0, 0);
#pragma unroll
      for (int m = 0; m < 4; ++m)
        acc[m][1] = __builtin_amdgcn_mfma_f32_16x16x32_f16(af[m][k], u1, acc[m][1], 0, 0, 0);
    }
    // epilogue: 32 compares, rare appends
#pragma unroll
    for (int m = 0; m < 4; ++m)
#pragma unroll
      for (int n = 0; n < 2; ++n)
#pragma unroll
        for (int r = 0; r < 4; ++r) {
          if (acc[m][n][r] >= Lthr[m][r]) {
            const int row = brow + wrow + m * 16 + l4 * 4 + r;
            const int code = c0seg + p * PAN + wc * 32 + n * 16 + l15;
            const int pos = atomicAdd(cnt + row, 1);
            if (pos < CAP) list[(size_t)row * CAP + pos] = (uint)code;
          }
        }
  }
}

// ---------------- kernel 5: exact recheck (bit-exact np chain) + gather ----------------
// 4 waves/block, 1 row per wave. z row staged in LDS; emb row prefetched in
// 8 register chunks so loads hide under the fma chain.
__global__ __launch_bounds__(256) void vq_recheck_gather(
    const float* __restrict__ z, const float* __restrict__ emb,
    const float* __restrict__ An, const int* __restrict__ cnt,
    const uint* __restrict__ list, float* __restrict__ out) {
  __shared__ float4 zsh[4][64];
  const int wv = threadIdx.x >> 6;
  const int lane = threadIdx.x & 63;
  const int row = blockIdx.x * 4 + wv;
  const float4* e4 = (const float4*)emb;

  zsh[wv][lane] = ((const float4*)z)[(size_t)row * D4 + lane];
  __syncthreads();

  const int nc = cnt[row];
  const float Ar = An[row];
  float bs = 3.4e38f;
  int bi = 0x7fffffff;

  if (nc <= CAP) {
    for (int c = lane; c < nc; c += 64) {
      const int code = (int)list[(size_t)row * CAP + c];
      const float4* ep = e4 + (size_t)code * D4;
      float p = 0.f;
#pragma unroll
      for (int ch = 0; ch < 8; ++ch) {
        float4 ev[8];
#pragma unroll
        for (int j = 0; j < 8; ++j) ev[j] = ep[ch * 8 + j];  // batched loads
#pragma unroll
        for (int j = 0; j < 8; ++j) {  // exact ascending-d fma chain
          const float4 zv = zsh[wv][ch * 8 + j];
          p = fmaf(zv.x, ev[j].x, p); p = fmaf(zv.y, ev[j].y, p);
          p = fmaf(zv.z, ev[j].z, p); p = fmaf(zv.w, ev[j].w, p);
        }
      }
      const float s = Ar - 2.0f * p;  // fl(A-2p), 2p exact
      if (s < bs || (s == bs && code < bi)) { bs = s; bi = code; }
    }
  } else {  // overflow fallback (P ~ 1e-8/row with 2048-code prepass): exact full scan
    for (int code = lane; code < KC; code += 64) {
      const float4* ep = e4 + (size_t)code * D4;
      float p = 0.f;
#pragma unroll 2
      for (int ch = 0; ch < 8; ++ch) {
        float4 ev[8];
#pragma unroll
        for (int j = 0; j < 8; ++j) ev[j] = ep[ch * 8 + j];
#pragma unroll
        for (int j = 0; j < 8; ++j) {
          const float4 zv = zsh[wv][ch * 8 + j];
          p = fmaf(zv.x, ev[j].x, p); p = fmaf(zv.y, ev[j].y, p);
          p = fmaf(zv.z, ev[j].z, p); p = fmaf(zv.w, ev[j].w, p);
        }
      }
      const float s = Ar - 2.0f * p;
      if (s < bs || (s == bs && code < bi)) { bs = s; bi = code; }
    }
  }
#pragma unroll
  for (int off = 1; off < 64; off <<= 1) {
    const float os = __shfl_xor(bs, off, 64);
    const int oi = __shfl_xor(bi, off, 64);
    if (os < bs || (os == bs && oi < bi)) { bs = os; bi = oi; }
  }
  const float4 v = e4[(size_t)bi * D4 + lane];
  ((float4*)out)[(size_t)row * D4 + lane] = v;
}

extern "C" void kernel_launch(void* const* d_in, const int* in_sizes, int n_in,
                              void* d_out, int out_size, void* d_ws, size_t ws_size,
                              hipStream_t stream) {
  const float* z = (const float*)d_in[0];    // [32768, 256] f32
  const float* emb = (const float*)d_in[1];  // [8192, 256] f32
  float* out = (float*)d_out;                // [32768, 256] f32

  char* wsb = (char*)d_ws;
  float* An = (float*)(wsb);                         // 128 KB
  int* cnt = (int*)(wsb + (128 << 10));              // 128 KB
  float* rowthr = (float*)(wsb + (256 << 10));       // 128 KB
  uint* list = (uint*)(wsb + (512 << 10));           // 32768*128*4B = 16 MB
  _Float16* z16 = (_Float16*)(wsb + (512 << 10) + (16 << 20));  // 16 MB
  _Float16* e16 = (_Float16*)(wsb + (512 << 10) + (32 << 20));  // 4 MB

  vq_znorm<<<NROWS / 256, 256, 0, stream>>>(z, An);
  vq_convert<<<2048, 256, 0, stream>>>(z, emb, z16, e16, cnt);
  vq_prepass<<<NROWS / MT, 256, 0, stream>>>(z16, e16, rowthr);
  vq_gemm_filter<<<2048, 256, 0, stream>>>(z16, e16, rowthr, cnt, list);
  vq_recheck_gather<<<NROWS / 4, 256, 0, stream>>>(z, emb, An, cnt, list, out);
}